// Round 18
// baseline (296.192 us; speedup 1.0000x reference)
//
#include <hip/hip_runtime.h>
#include <hip/hip_bf16.h>
#include <cstdint>
#include <cstddef>

#define NN 10000
#define NE 160000

typedef unsigned short u16;
typedef __attribute__((ext_vector_type(8))) short short8;
typedef __attribute__((ext_vector_type(4))) float f32x4;

__device__ __forceinline__ float b2f(u16 u){
    union { uint32_t i; float f; } v; v.i = ((uint32_t)u) << 16; return v.f;
}
__device__ __forceinline__ u16 f2b(float f){
    union { __hip_bfloat16 h; u16 u; } c; c.h = __float2bfloat16(f); return c.u;
}
// bit-exact RNE bf16 round for finite inputs: no NaN select (saves ~3 VALU/conv).
__device__ __forceinline__ u16 f2b_rne(float f){
    uint32_t b = __float_as_uint(f);
    return (u16)((b + 0x7FFFu + ((b >> 16) & 1u)) >> 16);
}
__device__ __forceinline__ float silu_f(float x){ return x / (1.f + __expf(-x)); }
__device__ __forceinline__ float ldr(const void* p, int i, int bf){
    return bf ? b2f(((const u16*)p)[i]) : ((const float*)p)[i];
}

// ---------------- workspace layout (4-byte word offsets) ----------------
constexpr size_t W_FLAG = 0;                        // 16 (flag[0] = anomaly count)
constexpr size_t W_CNT  = 16;                       // 10000
constexpr size_t W_OFFS = 10016;                    // 10001
constexpr size_t W_SSND = 30032;                    // 160000 (sender per sorted pos)
constexpr size_t W_ATT  = 350032;                   // 100000
constexpr size_t W_WGT  = 960032;
constexpr size_t OW_EMB = 0;
constexpr size_t OW_UP0 = 640;
constexpr size_t OW_R10 = 4736;
constexpr size_t OW_R20 = 5248;
constexpr size_t OW_R30 = 9344;
constexpr size_t OW_MIX0= 25728;
constexpr size_t OW_SC0 = 42112;
constexpr size_t OW_PR0 = 83072;
constexpr size_t OW_UP1 = 83264;
constexpr size_t OW_R11 = 87360;
constexpr size_t OW_R21 = 87872;
constexpr size_t OW_R31 = 91968;
constexpr size_t OW_MIX1= 108352;
constexpr size_t OW_SC1 = 124736;
constexpr size_t OW_PR1 = 165696;
constexpr size_t OW_RD0 = 165888;
constexpr size_t OW_ML1 = 165952;
constexpr size_t OW_ML2 = 166976;
constexpr size_t OW_TEND = 167000;
constexpr size_t W_BES  = W_WGT + OW_TEND;          // rank[E] (all tiers); fallback bessel reuses later (sequential)
constexpr size_t W_NF0  = W_BES + (size_t)NE*8;     // [N,64]
constexpr size_t W_H    = W_NF0 + (size_t)NN*64;
constexpr size_t W_A    = W_H   + (size_t)NN*64;    // h1 buffer in fused path; A in fallback
constexpr size_t W_NF1  = W_A   + (size_t)NN*64;
constexpr size_t W_R0   = W_NF1 + (size_t)NN*64;    // [E][64] bf16 flat, RECEIVER-SORTED
constexpr size_t W_R1   = W_R0  + (size_t)NE*32;
constexpr size_t WP_DUAL   = W_R1 + (size_t)NE*32;  // packed weights 2 x 10400 u16
constexpr size_t WP_SINGLE = W_R0 + (size_t)NE*32;
constexpr size_t W_RS_F = W_R0;                     // fallback: rs at R0 slot (no R in fallback)
constexpr size_t WP_F   = W_R0 + NE;                // fallback: dummy wpack target

constexpr size_t NEED_DUAL   = (WP_DUAL   + 10400) * 4;  // ~61 MB (ws measured ~268 MB)
constexpr size_t NEED_SINGLE = (WP_SINGLE + 10400) * 4;  // ~41 MB

constexpr int OCT  = 520;   // weight per-oct stride (u16)
constexpr int OCTS = 136;   // activation per-oct stride (u16), 16 rows

// ---------------- detect (dtype) + histogram with rank capture, one grid ----------------
__global__ void k_dh(const uint32_t* __restrict__ attrs, const int* __restrict__ rcv,
                     int* __restrict__ flag, int* __restrict__ cnt, int* __restrict__ rank){
    int i = blockIdx.x * 256 + threadIdx.x;          // 625*256 == NE
    int c = 0;
    if (i < 50000){
        uint32_t v = attrs[i];
        c = (v != 0u && v != 0x3F800000u) ? 1 : 0;
    }
    unsigned long long m = __ballot(c);
    if ((threadIdx.x & 63) == 0 && m)
        atomicAdd(flag, (int)__popcll(m));
    if (i < NE) rank[i] = atomicAdd(&cnt[rcv[i]], 1);
}

// ---------------- merged: scan (block 0) + convert (1..64) + wpack (65..66) + embed_h (67..691) ----------------
struct PrepArgs { const void* s[21]; float* d[21]; int n[21]; };
__global__ __launch_bounds__(1024) void k_scan_prep(PrepArgs a, const int* __restrict__ flag,
        const int* __restrict__ cnt, int* __restrict__ offs,
        u16* __restrict__ WP, float* __restrict__ nf0, float* __restrict__ h){
    int bf = flag[0] > 100;
    int t = threadIdx.x;
    if (blockIdx.x == 0){
        __shared__ int cl[10000];
        __shared__ int part[1024];
        for (int i = t; i < 10000; i += 1024) cl[i] = cnt[i];
        __syncthreads();
        int base = t * 10;
        int s = 0;
        #pragma unroll
        for (int i = 0; i < 10; i++) if (base + i < NN) s += cl[base + i];
        part[t] = s; __syncthreads();
        for (int d = 1; d < 1024; d <<= 1){
            int v = part[t];
            if (t >= d) v += part[t - d];
            __syncthreads();
            part[t] = v;
            __syncthreads();
        }
        int run = part[t] - s;
        #pragma unroll
        for (int i = 0; i < 10; i++){
            int idx = base + i;
            if (idx < NN){ offs[idx] = run; run += cl[idx]; }
        }
        if (t == 1023) offs[NN] = part[1023];
    } else if (blockIdx.x < 65){
        // vectorized convert: all n are %4==0, all dst word-offsets %4==0
        int stride = 64 * 1024;
        int t0 = (blockIdx.x - 1) * 1024 + t;
        for (int k = 0; k < 21; k++){
            float* d = a.d[k]; int n4 = a.n[k] >> 2;
            if (bf){
                const uint2* s = (const uint2*)a.s[k];
                for (int i = t0; i < n4; i += stride){
                    uint2 v = s[i];
                    float4 o;
                    o.x = b2f((u16)(v.x & 0xffffu));
                    o.y = b2f((u16)(v.x >> 16));
                    o.z = b2f((u16)(v.y & 0xffffu));
                    o.w = b2f((u16)(v.y >> 16));
                    ((float4*)d)[i] = o;
                }
            } else {
                const float4* s = (const float4*)a.s[k];
                for (int i = t0; i < n4; i += stride) ((float4*)d)[i] = s[i];
            }
        }
    } else if (blockIdx.x < 67){
        int b = blockIdx.x - 65;
        const void* W1 = a.s[b ? 12 : 5];
        const void* W2 = a.s[b ? 13 : 6];
        const void* W3 = a.s[b ? 14 : 7];
        u16* dst = WP + b * 10400;
        for (int i = t; i < 5200; i += 1024) ((uint32_t*)dst)[i] = 0;
        __syncthreads();
        for (int i = t; i < 512; i += 1024){
            int n = i >> 3, k = i & 7;
            dst[n*8 + k] = f2b(ldr(W1, k*64 + n, bf));
        }
        for (int i = t; i < 2048; i += 1024){
            int k = (i >> 6) * 2, n = i & 63;
            uint32_t p2 = ((uint32_t)f2b(ldr(W2, (k+1)*64 + n, bf)) << 16) | f2b(ldr(W2, k*64 + n, bf));
            uint32_t p3 = ((uint32_t)f2b(ldr(W3, (k+1)*256 + 4*n, bf)) << 16) | f2b(ldr(W3, k*256 + 4*n, bf));
            *(uint32_t*)&dst[2080 + (k>>3)*OCT + n*8 + (k&7)] = p2;
            *(uint32_t*)&dst[6240 + (k>>3)*OCT + n*8 + (k&7)] = p3;
        }
    } else {
        int nb = blockIdx.x - 67;                  // [0, 625): 16 nodes per block
        int n = nb*16 + (t >> 6);
        int l = t & 63;
        const void* attrs = a.s[1];
        const void* Wemb  = a.s[3];
        const void* Wup0  = a.s[4];
        float acc = 0.f;
        #pragma unroll
        for (int s = 0; s < 10; s++) acc += ldr(attrs, n*10 + s, bf) * ldr(Wemb, s*64 + l, bf);
        nf0[n*64 + l] = acc;
        float hv = 0.f;
        #pragma unroll 16
        for (int g = 0; g < 64; g++) hv += __shfl(acc, g) * ldr(Wup0, g*64 + l, bf);
        h[n*64 + l] = hv;
    }
}

// ---------------- scatter (fallback tier only; atomic-free via offs+rank) ----------------
__global__ void k_scatter_r(const int* __restrict__ rcv, const int* __restrict__ snd,
        const void* __restrict__ posr, const void* __restrict__ shfr,
        const int* __restrict__ offs, const int* __restrict__ rank,
        int* __restrict__ ssnd, float* __restrict__ rs,
        const int* __restrict__ flag){
    int e = blockIdx.x * 256 + threadIdx.x;
    if (e >= NE) return;
    int bf = flag[0] > 100;
    int r = rcv[e], s = snd[e];
    float vx = ldr(posr, r*3+0, bf) - ldr(posr, s*3+0, bf) + ldr(shfr, e*3+0, bf);
    float vy = ldr(posr, r*3+1, bf) - ldr(posr, s*3+1, bf) + ldr(shfr, e*3+1, bf);
    float vz = ldr(posr, r*3+2, bf) - ldr(posr, s*3+2, bf) + ldr(shfr, e*3+2, bf);
    float rr = sqrtf(vx*vx + vy*vy + vz*vz);
    int p = offs[r] + rank[e];
    ssnd[p] = s;
    rs[p] = rr;
}

// ---------------- bessel expansion (fallback tier only) ----------------
__global__ void k_bess(const float* __restrict__ rs, float* __restrict__ bessp){
    int p = blockIdx.x * 256 + threadIdx.x;
    if (p >= NE) return;
    float rr = rs[p];
    float xr = rr * 0.1f;
    float x2 = xr*xr; float x5 = x2*x2*xr;
    float env = 1.f - 21.f*x5 + 35.f*x5*xr - 15.f*x5*x2;
    if (xr >= 1.f) env = 0.f;
    float scl = 0.4472135954999579f * env / (rr + 1e-9f);
    float b[8];
    #pragma unroll
    for (int n = 1; n <= 8; n++)
        b[n-1] = scl * sinf((float)n * 3.14159265358979323846f * rr * 0.1f);
    float4* be = (float4*)(bessp + (size_t)p*8);
    be[0] = make_float4(b[0], b[1], b[2], b[3]);
    be[1] = make_float4(b[4], b[5], b[6], b[7]);
}

// ---------------- fused scatter + MFMA radial MLP (fused tiers) ----------------
// Wave owns 64 edges; edge metadata hoisted to the prologue (64 chains in flight).
// Stages consume registers via shfl. LDS: X = 12 octs/wave (layer2 overwrites
// layer1's octs 4-11; per-wave DS ops are in-order). f2b_rne (no NaN-select)
// for all hot-loop conversions.
__global__ __launch_bounds__(256) void k_mlp_mfma(
        const int* __restrict__ rcv, const int* __restrict__ snd,
        const void* __restrict__ posr, const void* __restrict__ shfr,
        const int* __restrict__ offs, const int* __restrict__ rank,
        const u16* __restrict__ WPa, const u16* __restrict__ WPb,
        int* __restrict__ ssnd, u16* __restrict__ R0, u16* __restrict__ R1,
        int nblk0, const int* __restrict__ flag){
    __shared__ __align__(16) u16 W[10400];
    __shared__ __align__(16) u16 X[4][12*OCTS];
    int bf = flag[0] > 100;
    int half = blockIdx.x >= nblk0;
    int blk  = half ? blockIdx.x - nblk0 : blockIdx.x;
    const u16* WP = half ? WPb : WPa;
    u16* R = half ? R1 : R0;
    int t = threadIdx.x;
    int w = t >> 6, lane = t & 63;
    int q = lane >> 4, r = lane & 15;
    u16* Xw = &X[w][0];
    // ---- prologue: stage weights + all 64 edges' metadata/distance/slot ----
    for (int i = t; i < 1300; i += 256) ((uint4*)W)[i] = ((const uint4*)WP)[i];
    int ge = blk*256 + w*64 + lane;        // lane's own edge
    int rn = rcv[ge], sn = snd[ge];
    int pv = offs[rn] + rank[ge];
    float vx = ldr(posr, rn*3+0, bf) - ldr(posr, sn*3+0, bf) + ldr(shfr, ge*3+0, bf);
    float vy = ldr(posr, rn*3+1, bf) - ldr(posr, sn*3+1, bf) + ldr(shfr, ge*3+1, bf);
    float vz = ldr(posr, rn*3+2, bf) - ldr(posr, sn*3+2, bf) + ldr(shfr, ge*3+2, bf);
    float rre = sqrtf(vx*vx + vy*vy + vz*vz);
    if (!half) ssnd[pv] = sn;
    {
        uint32_t* xz = (uint32_t*)(Xw + OCTS);
        for (int i = lane; i < 204; i += 64) xz[i] = 0;
    }
    __syncthreads();
    #pragma unroll 1
    for (int st = 0; st < 4; st++){
        int p0 = __shfl(pv, st*16 + q*4 + 0);
        int p1 = __shfl(pv, st*16 + q*4 + 1);
        int p2 = __shfl(pv, st*16 + q*4 + 2);
        int p3 = __shfl(pv, st*16 + q*4 + 3);
        // bessel from registers: lane covers (edge = lane>>2 of this stage, k = 2*(lane&3), +1)
        {
            float rr = __shfl(rre, st*16 + (lane >> 2));
            float xr = rr * 0.1f;
            float x2 = xr*xr, x5 = x2*x2*xr;
            float env = 1.f - 21.f*x5 + 35.f*x5*xr - 15.f*x5*x2;
            if (xr >= 1.f) env = 0.f;
            float scl = 0.4472135954999579f * env / (rr + 1e-9f);
            int k0 = (lane & 3) * 2;
            float b0 = scl * __sinf((float)(k0+1) * 0.3141592653589793f * rr);
            float b1 = scl * __sinf((float)(k0+2) * 0.3141592653589793f * rr);
            ((uint32_t*)Xw)[lane] = ((uint32_t)f2b_rne(b1) << 16) | f2b_rne(b0);
        }
        // ---- layer 1: K=8 (padded to 32), out -> octs 4..11 ----
        {
            short8 a = *(const short8*)&Xw[q*OCTS + r*8];
            #pragma unroll
            for (int nt = 0; nt < 4; nt++){
                short8 b = *(const short8*)&W[q*OCT + (nt*16 + r)*8];
                f32x4 c = {0.f, 0.f, 0.f, 0.f};
                c = __builtin_amdgcn_mfma_f32_16x16x32_bf16(a, b, c, 0, 0, 0);
                #pragma unroll
                for (int g = 0; g < 4; g++){
                    int e = q*4 + g;
                    int n = nt*16 + r;
                    Xw[(4 + (n>>3))*OCTS + e*8 + (n&7)] = f2b_rne(silu_f(c[g]));
                }
            }
        }
        // ---- layer 2: K=64; A-fragments to regs, then out OVERWRITES octs 4..11 ----
        {
            short8 a0 = *(const short8*)&Xw[(4+q)*OCTS + r*8];
            short8 a1 = *(const short8*)&Xw[(8+q)*OCTS + r*8];
            #pragma unroll
            for (int nt = 0; nt < 4; nt++){
                short8 b0 = *(const short8*)&W[2080 + q*OCT + (nt*16 + r)*8];
                short8 b1 = *(const short8*)&W[2080 + (4+q)*OCT + (nt*16 + r)*8];
                f32x4 c = {0.f, 0.f, 0.f, 0.f};
                c = __builtin_amdgcn_mfma_f32_16x16x32_bf16(a0, b0, c, 0, 0, 0);
                c = __builtin_amdgcn_mfma_f32_16x16x32_bf16(a1, b1, c, 0, 0, 0);
                #pragma unroll
                for (int g = 0; g < 4; g++){
                    int e = q*4 + g;
                    int n = nt*16 + r;
                    Xw[(4 + (n>>3))*OCTS + e*8 + (n&7)] = f2b_rne(silu_f(c[g]));
                }
            }
        }
        // ---- layer 3: K=64, store R to sorted slots ----
        {
            short8 a0 = *(const short8*)&Xw[(4+q)*OCTS + r*8];
            short8 a1 = *(const short8*)&Xw[(8+q)*OCTS + r*8];
            #pragma unroll
            for (int nt = 0; nt < 4; nt++){
                short8 b0 = *(const short8*)&W[6240 + q*OCT + (nt*16 + r)*8];
                short8 b1 = *(const short8*)&W[6240 + (4+q)*OCT + (nt*16 + r)*8];
                f32x4 c = {0.f, 0.f, 0.f, 0.f};
                c = __builtin_amdgcn_mfma_f32_16x16x32_bf16(a0, b0, c, 0, 0, 0);
                c = __builtin_amdgcn_mfma_f32_16x16x32_bf16(a1, b1, c, 0, 0, 0);
                int n = nt*16 + r;
                R[(size_t)p0*64 + n] = f2b_rne(c[0]);
                R[(size_t)p1*64 + n] = f2b_rne(c[1]);
                R[(size_t)p2*64 + n] = f2b_rne(c[2]);
                R[(size_t)p3*64 + n] = f2b_rne(c[3]);
            }
        }
    }
}

// ---------------- fused gather + node update + readout ----------------
// 4-way split accumulators break the 64-deep serial FMA chains in the
// am / sc / Wup1 / Wtail shfl-loops (16-deep chains, 4 in flight).
template<int LAST>
__global__ __launch_bounds__(256) void k_gnode(const int* __restrict__ offs,
        const int* __restrict__ ssnd, const float* __restrict__ h, const u16* __restrict__ R,
        const float* __restrict__ nf, const float* __restrict__ attrs,
        const float* __restrict__ Wmix0, const float* __restrict__ Wsc,
        const float* __restrict__ Wprod, const float* __restrict__ Wtail,
        const float* __restrict__ Wml2, const float* __restrict__ Wup1,
        float* __restrict__ nf1out, float* __restrict__ hout,
        void* __restrict__ out, const int* __restrict__ flag){
    int wv = threadIdx.x >> 6;
    int n  = blockIdx.x * 4 + wv;
    int l  = threadIdx.x & 63;
    int beg = __builtin_amdgcn_readfirstlane(offs[n]);
    int end = __builtin_amdgcn_readfirstlane(offs[n+1]);
    float acc = 0.f;
    // register-cached senders: one coalesced wave-load per 64-edge segment,
    // then v_readlane; 8-deep unroll keeps 16 loads in flight.
    for (int c = beg; c < end; c += 64){
        int ld = c + l; if (ld >= end) ld = end - 1;
        int sv = ssnd[ld];
        int m = end - c; if (m > 64) m = 64;
        int j = 0;
        for (; j + 8 <= m; j += 8){
            int s0 = __builtin_amdgcn_readlane(sv, j+0);
            int s1 = __builtin_amdgcn_readlane(sv, j+1);
            int s2 = __builtin_amdgcn_readlane(sv, j+2);
            int s3 = __builtin_amdgcn_readlane(sv, j+3);
            int s4 = __builtin_amdgcn_readlane(sv, j+4);
            int s5 = __builtin_amdgcn_readlane(sv, j+5);
            int s6 = __builtin_amdgcn_readlane(sv, j+6);
            int s7 = __builtin_amdgcn_readlane(sv, j+7);
            float r0 = b2f(R[(size_t)(c+j+0)*64 + l]);
            float r1 = b2f(R[(size_t)(c+j+1)*64 + l]);
            float r2 = b2f(R[(size_t)(c+j+2)*64 + l]);
            float r3 = b2f(R[(size_t)(c+j+3)*64 + l]);
            float r4 = b2f(R[(size_t)(c+j+4)*64 + l]);
            float r5 = b2f(R[(size_t)(c+j+5)*64 + l]);
            float r6 = b2f(R[(size_t)(c+j+6)*64 + l]);
            float r7 = b2f(R[(size_t)(c+j+7)*64 + l]);
            float a0 = h[s0*64 + l]*r0 + h[s1*64 + l]*r1;
            float a1 = h[s2*64 + l]*r2 + h[s3*64 + l]*r3;
            float a2 = h[s4*64 + l]*r4 + h[s5*64 + l]*r5;
            float a3 = h[s6*64 + l]*r6 + h[s7*64 + l]*r7;
            acc += (a0 + a1) + (a2 + a3);
        }
        for (; j + 4 <= m; j += 4){
            int s0 = __builtin_amdgcn_readlane(sv, j+0);
            int s1 = __builtin_amdgcn_readlane(sv, j+1);
            int s2 = __builtin_amdgcn_readlane(sv, j+2);
            int s3 = __builtin_amdgcn_readlane(sv, j+3);
            float r0 = b2f(R[(size_t)(c+j+0)*64 + l]);
            float r1 = b2f(R[(size_t)(c+j+1)*64 + l]);
            float r2 = b2f(R[(size_t)(c+j+2)*64 + l]);
            float r3 = b2f(R[(size_t)(c+j+3)*64 + l]);
            acc += h[s0*64 + l]*r0 + h[s1*64 + l]*r1 + h[s2*64 + l]*r2 + h[s3*64 + l]*r3;
        }
        for (; j < m; j++){
            int s = __builtin_amdgcn_readlane(sv, j);
            acc += h[s*64 + l] * b2f(R[(size_t)(c+j)*64 + l]);
        }
    }
    float Af  = acc * 0.0625f;
    float nff = nf[n*64 + l];
    float am0 = 0.f, am1 = 0.f, am2 = 0.f, am3 = 0.f;
    #pragma unroll
    for (int f = 0; f < 64; f += 4){
        am0 += __shfl(Af, f+0) * Wmix0[(f+0)*64 + l];
        am1 += __shfl(Af, f+1) * Wmix0[(f+1)*64 + l];
        am2 += __shfl(Af, f+2) * Wmix0[(f+2)*64 + l];
        am3 += __shfl(Af, f+3) * Wmix0[(f+3)*64 + l];
    }
    float am = (am0 + am1) + (am2 + am3);
    float sc = 0.f;
    for (int s = 0; s < 10; s++){
        float av = attrs[n*10 + s];       // wave-uniform
        if (av != 0.f){
            const float* Ws = Wsc + s*4096;
            float t0 = 0.f, t1 = 0.f, t2 = 0.f, t3 = 0.f;
            #pragma unroll
            for (int f = 0; f < 64; f += 4){
                t0 += __shfl(nff, f+0) * Ws[(f+0)*64 + l];
                t1 += __shfl(nff, f+1) * Ws[(f+1)*64 + l];
                t2 += __shfl(nff, f+2) * Ws[(f+2)*64 + l];
                t3 += __shfl(nff, f+3) * Ws[(f+3)*64 + l];
            }
            sc += av * ((t0 + t1) + (t2 + t3));
        }
    }
    float poly = Wprod[l] + Wprod[64 + l]*am + Wprod[128 + l]*am*am;
    float val = am*poly + sc;
    float rv;
    if (LAST == 0){
        nf1out[n*64 + l] = val;
        float h0 = 0.f, h1 = 0.f, h2 = 0.f, h3 = 0.f;
        #pragma unroll
        for (int g = 0; g < 64; g += 4){
            h0 += __shfl(val, g+0) * Wup1[(g+0)*64 + l];
            h1 += __shfl(val, g+1) * Wup1[(g+1)*64 + l];
            h2 += __shfl(val, g+2) * Wup1[(g+2)*64 + l];
            h3 += __shfl(val, g+3) * Wup1[(g+3)*64 + l];
        }
        hout[n*64 + l] = (h0 + h1) + (h2 + h3);   // separate buffer: h still being gathered elsewhere
        rv = val * Wtail[l];
    } else {
        int lj = l & 15;                  // all 64 lanes run the shfl loop (divergent shfl is UB)
        float t0 = 0.f, t1 = 0.f, t2 = 0.f, t3 = 0.f;
        #pragma unroll
        for (int g = 0; g < 64; g += 4){
            t0 += __shfl(val, g+0) * Wtail[(g+0)*16 + lj];
            t1 += __shfl(val, g+1) * Wtail[(g+1)*16 + lj];
            t2 += __shfl(val, g+2) * Wtail[(g+2)*16 + lj];
            t3 += __shfl(val, g+3) * Wtail[(g+3)*16 + lj];
        }
        float tt = (t0 + t1) + (t2 + t3);
        rv = (l < 16) ? (silu_f(tt) * Wml2[lj]) : 0.f;
    }
    #pragma unroll
    for (int o2 = 32; o2; o2 >>= 1) rv += __shfl_down(rv, o2);
    if (l == 0){
        int idx = 2*n + LAST;
        if (flag[0] > 100) ((__hip_bfloat16*)out)[idx] = __float2bfloat16(rv);
        else               ((float*)out)[idx] = rv;
    }
}

// ---------------- legacy fused msg + node (fallback tier only) ----------------
__global__ __launch_bounds__(256) void k_msg_fused(const int* __restrict__ offs,
        const int* __restrict__ ssnd, const float* __restrict__ h, const float* __restrict__ bessp,
        const float* __restrict__ W1, const float* __restrict__ W2, const float* __restrict__ W3,
        float* __restrict__ A){
    int wv = threadIdx.x >> 6;
    int n  = blockIdx.x * 4 + wv;
    int l  = threadIdx.x & 63;
    float w1c[8];
    #pragma unroll
    for (int i = 0; i < 8; i++) w1c[i] = W1[i*64 + l];
    float w2c[64];
    #pragma unroll
    for (int j = 0; j < 64; j++) w2c[j] = W2[j*64 + l];
    float w3c[64];
    #pragma unroll
    for (int j = 0; j < 64; j++) w3c[j] = W3[j*256 + 4*l];
    float acc = 0.f;
    int beg = __builtin_amdgcn_readfirstlane(offs[n]);
    int end = __builtin_amdgcn_readfirstlane(offs[n+1]);
    for (int p = beg; p < end; p++){
        int s = __builtin_amdgcn_readfirstlane(ssnd[p]);
        const float* be = bessp + (size_t)p*8;
        float h1 = 0.f;
        #pragma unroll
        for (int i = 0; i < 8; i++) h1 += be[i] * w1c[i];
        h1 = silu_f(h1);
        float h2 = 0.f;
        #pragma unroll
        for (int j = 0; j < 64; j++) h2 += __shfl(h1, j) * w2c[j];
        h2 = silu_f(h2);
        float rr = 0.f;
        #pragma unroll
        for (int j = 0; j < 64; j++) rr += __shfl(h2, j) * w3c[j];
        acc += h[s*64 + l] * rr;
    }
    A[n*64 + l] = acc * 0.0625f;
}
template<int LAST>
__global__ __launch_bounds__(256) void k_node(const float* __restrict__ A, const float* __restrict__ nf,
        const float* __restrict__ attrs, const float* __restrict__ Wmix0, const float* __restrict__ Wsc,
        const float* __restrict__ Wprod, const float* __restrict__ Wtail, const float* __restrict__ Wml2,
        const float* __restrict__ Wup1, float* __restrict__ nf1out, float* __restrict__ hout,
        void* __restrict__ out, const int* __restrict__ flag){
    int wv = threadIdx.x >> 6;
    int n  = blockIdx.x * 4 + wv;
    int l  = threadIdx.x & 63;
    float Af  = A[n*64 + l];
    float nff = nf[n*64 + l];
    float am = 0.f;
    #pragma unroll 16
    for (int f = 0; f < 64; f++) am += __shfl(Af, f) * Wmix0[f*64 + l];
    float sc = 0.f;
    for (int s = 0; s < 10; s++){
        float av = attrs[n*10 + s];
        if (av != 0.f){
            const float* Ws = Wsc + s*4096;
            float t = 0.f;
            #pragma unroll 16
            for (int f = 0; f < 64; f++) t += __shfl(nff, f) * Ws[f*64 + l];
            sc += av * t;
        }
    }
    float poly = Wprod[l] + Wprod[64 + l]*am + Wprod[128 + l]*am*am;
    float val = am*poly + sc;
    float rv;
    if (LAST == 0){
        nf1out[n*64 + l] = val;
        float hv = 0.f;
        #pragma unroll 16
        for (int g = 0; g < 64; g++) hv += __shfl(val, g) * Wup1[g*64 + l];
        hout[n*64 + l] = hv;
        rv = val * Wtail[l];
    } else {
        int lj = l & 15;
        float t = 0.f;
        #pragma unroll 16
        for (int g = 0; g < 64; g++){
            float vg = __shfl(val, g);
            t += vg * Wtail[g*16 + lj];
        }
        rv = (l < 16) ? (silu_f(t) * Wml2[lj]) : 0.f;
    }
    #pragma unroll
    for (int o2 = 32; o2; o2 >>= 1) rv += __shfl_down(rv, o2);
    if (l == 0){
        int idx = 2*n + LAST;
        if (flag[0] > 100) ((__hip_bfloat16*)out)[idx] = __float2bfloat16(rv);
        else               ((float*)out)[idx] = rv;
    }
}

// ---------------- launch ----------------
extern "C" void kernel_launch(void* const* d_in, const int* in_sizes, int n_in,
                              void* d_out, int out_size, void* d_ws, size_t ws_size,
                              hipStream_t stream) {
    int*   iw = (int*)d_ws;
    float* fw = (float*)d_ws;
    const int* snd = (const int*)d_in[3];
    const int* rcv = (const int*)d_in[4];

    PrepArgs pa;
    const int    pidx[21] = {0,1,2, 5,6,7,8,9,10,11,12,13,14,15,16,17,18,19,20,21,22};
    const size_t pdst[21] = {W_ATT, W_ATT, W_ATT,      // slots 0,2 dead (n=0); 1 = attrs
        W_WGT+OW_EMB, W_WGT+OW_UP0, W_WGT+OW_R10, W_WGT+OW_R20, W_WGT+OW_R30,
        W_WGT+OW_MIX0, W_WGT+OW_SC0, W_WGT+OW_PR0,
        W_WGT+OW_UP1, W_WGT+OW_R11, W_WGT+OW_R21, W_WGT+OW_R31,
        W_WGT+OW_MIX1, W_WGT+OW_SC1, W_WGT+OW_PR1,
        W_WGT+OW_RD0, W_WGT+OW_ML1, W_WGT+OW_ML2};
    // pos (0) and shifts (2) conversions are DEAD (mlp/scatter read raw inputs) -> n=0
    const int    pn[21]   = {0, 100000, 0,
        640, 4096, 512, 4096, 16384, 16384, 40960, 192,
        4096, 512, 4096, 16384, 16384, 40960, 192, 64, 1024, 16};
    for (int i = 0; i < 21; i++){
        pa.s[i] = d_in[pidx[i]];
        pa.d[i] = fw + pdst[i];
        pa.n[i] = pn[i];
    }

    const int dual   = (ws_size >= NEED_DUAL);
    const int single = (!dual && ws_size >= NEED_SINGLE);
    const size_t wp  = dual ? WP_DUAL : (single ? WP_SINGLE : WP_F);
    int* rank = iw + W_BES;   // [E]; fallback bessel reuses this region strictly after scatter

    hipMemsetAsync(iw, 0, (W_CNT + NN) * sizeof(int), stream);   // flag + cnt
    k_dh<<<NE/256, 256, 0, stream>>>((const uint32_t*)d_in[1], rcv, iw + W_FLAG, iw + W_CNT, rank);
    k_scan_prep<<<692, 1024, 0, stream>>>(pa, iw + W_FLAG, iw + W_CNT, iw + W_OFFS,
                                          (u16*)(fw + wp), fw + W_NF0, fw + W_H);

    if (dual){
        k_mlp_mfma<<<1250, 256, 0, stream>>>(rcv, snd, d_in[0], d_in[2],
                                             iw + W_OFFS, rank,
                                             (const u16*)(fw + wp), (const u16*)(fw + wp) + 10400,
                                             iw + W_SSND, (u16*)(fw + W_R0), (u16*)(fw + W_R1),
                                             625, iw + W_FLAG);
        k_gnode<0><<<NN/4, 256, 0, stream>>>(iw+W_OFFS, iw+W_SSND, fw+W_H, (const u16*)(fw+W_R0),
            fw+W_NF0, fw+W_ATT, fw+W_WGT+OW_MIX0, fw+W_WGT+OW_SC0, fw+W_WGT+OW_PR0,
            fw+W_WGT+OW_RD0, nullptr, fw+W_WGT+OW_UP1, fw+W_NF1, fw+W_A, d_out, iw+W_FLAG);
        k_gnode<1><<<NN/4, 256, 0, stream>>>(iw+W_OFFS, iw+W_SSND, fw+W_A, (const u16*)(fw+W_R1),
            fw+W_NF1, fw+W_ATT, fw+W_WGT+OW_MIX1, fw+W_WGT+OW_SC1, fw+W_WGT+OW_PR1,
            fw+W_WGT+OW_ML1, fw+W_WGT+OW_ML2, nullptr, nullptr, nullptr, d_out, iw+W_FLAG);
    } else if (single){
        k_mlp_mfma<<<625, 256, 0, stream>>>(rcv, snd, d_in[0], d_in[2],
                                            iw + W_OFFS, rank,
                                            (const u16*)(fw + wp), (const u16*)(fw + wp),
                                            iw + W_SSND, (u16*)(fw + W_R0), (u16*)(fw + W_R0),
                                            2000000, iw + W_FLAG);
        k_gnode<0><<<NN/4, 256, 0, stream>>>(iw+W_OFFS, iw+W_SSND, fw+W_H, (const u16*)(fw+W_R0),
            fw+W_NF0, fw+W_ATT, fw+W_WGT+OW_MIX0, fw+W_WGT+OW_SC0, fw+W_WGT+OW_PR0,
            fw+W_WGT+OW_RD0, nullptr, fw+W_WGT+OW_UP1, fw+W_NF1, fw+W_A, d_out, iw+W_FLAG);
        k_mlp_mfma<<<625, 256, 0, stream>>>(rcv, snd, d_in[0], d_in[2],
                                            iw + W_OFFS, rank,
                                            (const u16*)(fw + wp) + 10400, (const u16*)(fw + wp) + 10400,
                                            iw + W_SSND, (u16*)(fw + W_R0), (u16*)(fw + W_R0),
                                            2000000, iw + W_FLAG);
        k_gnode<1><<<NN/4, 256, 0, stream>>>(iw+W_OFFS, iw+W_SSND, fw+W_A, (const u16*)(fw+W_R0),
            fw+W_NF1, fw+W_ATT, fw+W_WGT+OW_MIX1, fw+W_WGT+OW_SC1, fw+W_WGT+OW_PR1,
            fw+W_WGT+OW_ML1, fw+W_WGT+OW_ML2, nullptr, nullptr, nullptr, d_out, iw+W_FLAG);
    } else {
        // fallback tier: scatter + bessel buffer + VALU msg kernels (rs lives at W_R0 slot)
        k_scatter_r<<<NE/256, 256, 0, stream>>>(rcv, snd, d_in[0], d_in[2],
                                                iw + W_OFFS, rank, iw + W_SSND,
                                                fw + W_RS_F, iw + W_FLAG);
        k_bess<<<NE/256, 256, 0, stream>>>(fw + W_RS_F, fw + W_BES);
        k_msg_fused<<<NN/4, 256, 0, stream>>>(iw+W_OFFS, iw+W_SSND, fw+W_H, fw+W_BES,
                                              fw+W_WGT+OW_R10, fw+W_WGT+OW_R20,
                                              fw+W_WGT+OW_R30, fw + W_A);
        k_node<0><<<NN/4, 256, 0, stream>>>(fw + W_A, fw + W_NF0, fw + W_ATT,
                                            fw + W_WGT + OW_MIX0, fw + W_WGT + OW_SC0,
                                            fw + W_WGT + OW_PR0, fw + W_WGT + OW_RD0, nullptr,
                                            fw + W_WGT + OW_UP1, fw + W_NF1, fw + W_H,
                                            d_out, iw + W_FLAG);
        k_msg_fused<<<NN/4, 256, 0, stream>>>(iw+W_OFFS, iw+W_SSND, fw+W_H, fw+W_BES,
                                              fw+W_WGT+OW_R11, fw+W_WGT+OW_R21,
                                              fw+W_WGT+OW_R31, fw + W_A);
        k_node<1><<<NN/4, 256, 0, stream>>>(fw + W_A, fw + W_NF1, fw + W_ATT,
                                            fw + W_WGT + OW_MIX1, fw + W_WGT + OW_SC1,
                                            fw + W_WGT + OW_PR1, fw + W_WGT + OW_ML1,
                                            fw + W_WGT + OW_ML2, nullptr, nullptr, nullptr,
                                            d_out, iw + W_FLAG);
    }
}

// Round 19
// 213.481 us; speedup vs baseline: 1.3874x; 1.3874x over previous
//
#include <hip/hip_runtime.h>
#include <hip/hip_bf16.h>
#include <cstdint>
#include <cstddef>

#define NN 10000
#define NE 160000

typedef unsigned short u16;
typedef __attribute__((ext_vector_type(8))) short short8;
typedef __attribute__((ext_vector_type(4))) float f32x4;

__device__ __forceinline__ float b2f(u16 u){
    union { uint32_t i; float f; } v; v.i = ((uint32_t)u) << 16; return v.f;
}
__device__ __forceinline__ u16 f2b(float f){
    union { __hip_bfloat16 h; u16 u; } c; c.h = __float2bfloat16(f); return c.u;
}
// bit-exact RNE bf16 round for finite inputs: no NaN select (saves ~3 VALU/conv).
__device__ __forceinline__ u16 f2b_rne(float f){
    uint32_t b = __float_as_uint(f);
    return (u16)((b + 0x7FFFu + ((b >> 16) & 1u)) >> 16);
}
__device__ __forceinline__ float silu_f(float x){ return x / (1.f + __expf(-x)); }
__device__ __forceinline__ float ldr(const void* p, int i, int bf){
    return bf ? b2f(((const u16*)p)[i]) : ((const float*)p)[i];
}

// ---------------- workspace layout (4-byte word offsets) ----------------
constexpr size_t W_FLAG = 0;                        // 16 (flag[0] = anomaly count)
constexpr size_t W_CNT  = 16;                       // 10000
constexpr size_t W_OFFS = 10016;                    // 10001
constexpr size_t W_SSND = 30032;                    // 160000 (sender per sorted pos)
constexpr size_t W_ATT  = 350032;                   // 100000
constexpr size_t W_WGT  = 960032;
constexpr size_t OW_EMB = 0;
constexpr size_t OW_UP0 = 640;
constexpr size_t OW_R10 = 4736;
constexpr size_t OW_R20 = 5248;
constexpr size_t OW_R30 = 9344;
constexpr size_t OW_MIX0= 25728;
constexpr size_t OW_SC0 = 42112;
constexpr size_t OW_PR0 = 83072;
constexpr size_t OW_UP1 = 83264;
constexpr size_t OW_R11 = 87360;
constexpr size_t OW_R21 = 87872;
constexpr size_t OW_R31 = 91968;
constexpr size_t OW_MIX1= 108352;
constexpr size_t OW_SC1 = 124736;
constexpr size_t OW_PR1 = 165696;
constexpr size_t OW_RD0 = 165888;
constexpr size_t OW_ML1 = 165952;
constexpr size_t OW_ML2 = 166976;
constexpr size_t OW_TEND = 167000;
constexpr size_t W_BES  = W_WGT + OW_TEND;          // rank[E] (all tiers); fallback bessel reuses later (sequential)
constexpr size_t W_NF0  = W_BES + (size_t)NE*8;     // [N,64]
constexpr size_t W_H    = W_NF0 + (size_t)NN*64;
constexpr size_t W_A    = W_H   + (size_t)NN*64;    // h1 buffer in fused path; A in fallback
constexpr size_t W_NF1  = W_A   + (size_t)NN*64;
constexpr size_t W_R0   = W_NF1 + (size_t)NN*64;    // [E][64] bf16 flat, RECEIVER-SORTED
constexpr size_t W_R1   = W_R0  + (size_t)NE*32;
constexpr size_t WP_DUAL   = W_R1 + (size_t)NE*32;  // packed weights 2 x 10400 u16
constexpr size_t WP_SINGLE = W_R0 + (size_t)NE*32;
constexpr size_t W_RS_F = W_R0;                     // fallback: rs at R0 slot (no R in fallback)
constexpr size_t WP_F   = W_R0 + NE;                // fallback: dummy wpack target

constexpr size_t NEED_DUAL   = (WP_DUAL   + 10400) * 4;  // ~61 MB (ws measured ~268 MB)
constexpr size_t NEED_SINGLE = (WP_SINGLE + 10400) * 4;  // ~41 MB

constexpr int OCT  = 520;   // weight per-oct stride (u16)
constexpr int OCTS = 136;   // activation per-oct stride (u16), 16 rows

// ---------------- detect (dtype) + histogram with rank capture, one grid ----------------
__global__ void k_dh(const uint32_t* __restrict__ attrs, const int* __restrict__ rcv,
                     int* __restrict__ flag, int* __restrict__ cnt, int* __restrict__ rank){
    int i = blockIdx.x * 256 + threadIdx.x;          // 625*256 == NE
    int c = 0;
    if (i < 50000){
        uint32_t v = attrs[i];
        c = (v != 0u && v != 0x3F800000u) ? 1 : 0;
    }
    unsigned long long m = __ballot(c);
    if ((threadIdx.x & 63) == 0 && m)
        atomicAdd(flag, (int)__popcll(m));
    if (i < NE) rank[i] = atomicAdd(&cnt[rcv[i]], 1);
}

// ---------------- merged: scan (block 0) + convert (1..64) + wpack (65..66) + embed_h (67..691) ----------------
struct PrepArgs { const void* s[21]; float* d[21]; int n[21]; };
__global__ __launch_bounds__(1024) void k_scan_prep(PrepArgs a, const int* __restrict__ flag,
        const int* __restrict__ cnt, int* __restrict__ offs,
        u16* __restrict__ WP, float* __restrict__ nf0, float* __restrict__ h){
    int bf = flag[0] > 100;
    int t = threadIdx.x;
    if (blockIdx.x == 0){
        __shared__ int cl[10000];
        __shared__ int part[1024];
        for (int i = t; i < 10000; i += 1024) cl[i] = cnt[i];
        __syncthreads();
        int base = t * 10;
        int s = 0;
        #pragma unroll
        for (int i = 0; i < 10; i++) if (base + i < NN) s += cl[base + i];
        part[t] = s; __syncthreads();
        for (int d = 1; d < 1024; d <<= 1){
            int v = part[t];
            if (t >= d) v += part[t - d];
            __syncthreads();
            part[t] = v;
            __syncthreads();
        }
        int run = part[t] - s;
        #pragma unroll
        for (int i = 0; i < 10; i++){
            int idx = base + i;
            if (idx < NN){ offs[idx] = run; run += cl[idx]; }
        }
        if (t == 1023) offs[NN] = part[1023];
    } else if (blockIdx.x < 65){
        // vectorized convert: all n are %4==0, all dst word-offsets %4==0
        int stride = 64 * 1024;
        int t0 = (blockIdx.x - 1) * 1024 + t;
        for (int k = 0; k < 21; k++){
            float* d = a.d[k]; int n4 = a.n[k] >> 2;
            if (bf){
                const uint2* s = (const uint2*)a.s[k];
                for (int i = t0; i < n4; i += stride){
                    uint2 v = s[i];
                    float4 o;
                    o.x = b2f((u16)(v.x & 0xffffu));
                    o.y = b2f((u16)(v.x >> 16));
                    o.z = b2f((u16)(v.y & 0xffffu));
                    o.w = b2f((u16)(v.y >> 16));
                    ((float4*)d)[i] = o;
                }
            } else {
                const float4* s = (const float4*)a.s[k];
                for (int i = t0; i < n4; i += stride) ((float4*)d)[i] = s[i];
            }
        }
    } else if (blockIdx.x < 67){
        int b = blockIdx.x - 65;
        const void* W1 = a.s[b ? 12 : 5];
        const void* W2 = a.s[b ? 13 : 6];
        const void* W3 = a.s[b ? 14 : 7];
        u16* dst = WP + b * 10400;
        for (int i = t; i < 5200; i += 1024) ((uint32_t*)dst)[i] = 0;
        __syncthreads();
        for (int i = t; i < 512; i += 1024){
            int n = i >> 3, k = i & 7;
            dst[n*8 + k] = f2b(ldr(W1, k*64 + n, bf));
        }
        for (int i = t; i < 2048; i += 1024){
            int k = (i >> 6) * 2, n = i & 63;
            uint32_t p2 = ((uint32_t)f2b(ldr(W2, (k+1)*64 + n, bf)) << 16) | f2b(ldr(W2, k*64 + n, bf));
            uint32_t p3 = ((uint32_t)f2b(ldr(W3, (k+1)*256 + 4*n, bf)) << 16) | f2b(ldr(W3, k*256 + 4*n, bf));
            *(uint32_t*)&dst[2080 + (k>>3)*OCT + n*8 + (k&7)] = p2;
            *(uint32_t*)&dst[6240 + (k>>3)*OCT + n*8 + (k&7)] = p3;
        }
    } else {
        int nb = blockIdx.x - 67;                  // [0, 625): 16 nodes per block
        int n = nb*16 + (t >> 6);
        int l = t & 63;
        const void* attrs = a.s[1];
        const void* Wemb  = a.s[3];
        const void* Wup0  = a.s[4];
        float acc = 0.f;
        #pragma unroll
        for (int s = 0; s < 10; s++) acc += ldr(attrs, n*10 + s, bf) * ldr(Wemb, s*64 + l, bf);
        nf0[n*64 + l] = acc;
        float hv = 0.f;
        #pragma unroll 16
        for (int g = 0; g < 64; g++) hv += __shfl(acc, g) * ldr(Wup0, g*64 + l, bf);
        h[n*64 + l] = hv;
    }
}

// ---------------- scatter (fallback tier only; atomic-free via offs+rank) ----------------
__global__ void k_scatter_r(const int* __restrict__ rcv, const int* __restrict__ snd,
        const void* __restrict__ posr, const void* __restrict__ shfr,
        const int* __restrict__ offs, const int* __restrict__ rank,
        int* __restrict__ ssnd, float* __restrict__ rs,
        const int* __restrict__ flag){
    int e = blockIdx.x * 256 + threadIdx.x;
    if (e >= NE) return;
    int bf = flag[0] > 100;
    int r = rcv[e], s = snd[e];
    float vx = ldr(posr, r*3+0, bf) - ldr(posr, s*3+0, bf) + ldr(shfr, e*3+0, bf);
    float vy = ldr(posr, r*3+1, bf) - ldr(posr, s*3+1, bf) + ldr(shfr, e*3+1, bf);
    float vz = ldr(posr, r*3+2, bf) - ldr(posr, s*3+2, bf) + ldr(shfr, e*3+2, bf);
    float rr = sqrtf(vx*vx + vy*vy + vz*vz);
    int p = offs[r] + rank[e];
    ssnd[p] = s;
    rs[p] = rr;
}

// ---------------- bessel expansion (fallback tier only) ----------------
__global__ void k_bess(const float* __restrict__ rs, float* __restrict__ bessp){
    int p = blockIdx.x * 256 + threadIdx.x;
    if (p >= NE) return;
    float rr = rs[p];
    float xr = rr * 0.1f;
    float x2 = xr*xr; float x5 = x2*x2*xr;
    float env = 1.f - 21.f*x5 + 35.f*x5*xr - 15.f*x5*x2;
    if (xr >= 1.f) env = 0.f;
    float scl = 0.4472135954999579f * env / (rr + 1e-9f);
    float b[8];
    #pragma unroll
    for (int n = 1; n <= 8; n++)
        b[n-1] = scl * sinf((float)n * 3.14159265358979323846f * rr * 0.1f);
    float4* be = (float4*)(bessp + (size_t)p*8);
    be[0] = make_float4(b[0], b[1], b[2], b[3]);
    be[1] = make_float4(b[4], b[5], b[6], b[7]);
}

// ---------------- fused scatter + MFMA radial MLP (fused tiers) ----------------
// Wave owns 64 edges; edge metadata hoisted to the prologue (64 chains in flight).
// Stages consume registers via shfl. LDS: X = 12 octs/wave (layer2 overwrites
// layer1's octs 4-11; per-wave DS ops are in-order). f2b_rne (no NaN-select)
// for all hot-loop conversions.
__global__ __launch_bounds__(256) void k_mlp_mfma(
        const int* __restrict__ rcv, const int* __restrict__ snd,
        const void* __restrict__ posr, const void* __restrict__ shfr,
        const int* __restrict__ offs, const int* __restrict__ rank,
        const u16* __restrict__ WPa, const u16* __restrict__ WPb,
        int* __restrict__ ssnd, u16* __restrict__ R0, u16* __restrict__ R1,
        int nblk0, const int* __restrict__ flag){
    __shared__ __align__(16) u16 W[10400];
    __shared__ __align__(16) u16 X[4][12*OCTS];
    int bf = flag[0] > 100;
    int half = blockIdx.x >= nblk0;
    int blk  = half ? blockIdx.x - nblk0 : blockIdx.x;
    const u16* WP = half ? WPb : WPa;
    u16* R = half ? R1 : R0;
    int t = threadIdx.x;
    int w = t >> 6, lane = t & 63;
    int q = lane >> 4, r = lane & 15;
    u16* Xw = &X[w][0];
    // ---- prologue: stage weights + all 64 edges' metadata/distance/slot ----
    for (int i = t; i < 1300; i += 256) ((uint4*)W)[i] = ((const uint4*)WP)[i];
    int ge = blk*256 + w*64 + lane;        // lane's own edge
    int rn = rcv[ge], sn = snd[ge];
    int pv = offs[rn] + rank[ge];
    float vx = ldr(posr, rn*3+0, bf) - ldr(posr, sn*3+0, bf) + ldr(shfr, ge*3+0, bf);
    float vy = ldr(posr, rn*3+1, bf) - ldr(posr, sn*3+1, bf) + ldr(shfr, ge*3+1, bf);
    float vz = ldr(posr, rn*3+2, bf) - ldr(posr, sn*3+2, bf) + ldr(shfr, ge*3+2, bf);
    float rre = sqrtf(vx*vx + vy*vy + vz*vz);
    if (!half) ssnd[pv] = sn;
    {
        uint32_t* xz = (uint32_t*)(Xw + OCTS);
        for (int i = lane; i < 204; i += 64) xz[i] = 0;
    }
    __syncthreads();
    #pragma unroll 1
    for (int st = 0; st < 4; st++){
        int p0 = __shfl(pv, st*16 + q*4 + 0);
        int p1 = __shfl(pv, st*16 + q*4 + 1);
        int p2 = __shfl(pv, st*16 + q*4 + 2);
        int p3 = __shfl(pv, st*16 + q*4 + 3);
        // bessel from registers: lane covers (edge = lane>>2 of this stage, k = 2*(lane&3), +1)
        {
            float rr = __shfl(rre, st*16 + (lane >> 2));
            float xr = rr * 0.1f;
            float x2 = xr*xr, x5 = x2*x2*xr;
            float env = 1.f - 21.f*x5 + 35.f*x5*xr - 15.f*x5*x2;
            if (xr >= 1.f) env = 0.f;
            float scl = 0.4472135954999579f * env / (rr + 1e-9f);
            int k0 = (lane & 3) * 2;
            float b0 = scl * __sinf((float)(k0+1) * 0.3141592653589793f * rr);
            float b1 = scl * __sinf((float)(k0+2) * 0.3141592653589793f * rr);
            ((uint32_t*)Xw)[lane] = ((uint32_t)f2b_rne(b1) << 16) | f2b_rne(b0);
        }
        // ---- layer 1: K=8 (padded to 32), out -> octs 4..11 ----
        {
            short8 a = *(const short8*)&Xw[q*OCTS + r*8];
            #pragma unroll
            for (int nt = 0; nt < 4; nt++){
                short8 b = *(const short8*)&W[q*OCT + (nt*16 + r)*8];
                f32x4 c = {0.f, 0.f, 0.f, 0.f};
                c = __builtin_amdgcn_mfma_f32_16x16x32_bf16(a, b, c, 0, 0, 0);
                #pragma unroll
                for (int g = 0; g < 4; g++){
                    int e = q*4 + g;
                    int n = nt*16 + r;
                    Xw[(4 + (n>>3))*OCTS + e*8 + (n&7)] = f2b_rne(silu_f(c[g]));
                }
            }
        }
        // ---- layer 2: K=64; A-fragments to regs, then out OVERWRITES octs 4..11 ----
        {
            short8 a0 = *(const short8*)&Xw[(4+q)*OCTS + r*8];
            short8 a1 = *(const short8*)&Xw[(8+q)*OCTS + r*8];
            #pragma unroll
            for (int nt = 0; nt < 4; nt++){
                short8 b0 = *(const short8*)&W[2080 + q*OCT + (nt*16 + r)*8];
                short8 b1 = *(const short8*)&W[2080 + (4+q)*OCT + (nt*16 + r)*8];
                f32x4 c = {0.f, 0.f, 0.f, 0.f};
                c = __builtin_amdgcn_mfma_f32_16x16x32_bf16(a0, b0, c, 0, 0, 0);
                c = __builtin_amdgcn_mfma_f32_16x16x32_bf16(a1, b1, c, 0, 0, 0);
                #pragma unroll
                for (int g = 0; g < 4; g++){
                    int e = q*4 + g;
                    int n = nt*16 + r;
                    Xw[(4 + (n>>3))*OCTS + e*8 + (n&7)] = f2b_rne(silu_f(c[g]));
                }
            }
        }
        // ---- layer 3: K=64, store R to sorted slots ----
        {
            short8 a0 = *(const short8*)&Xw[(4+q)*OCTS + r*8];
            short8 a1 = *(const short8*)&Xw[(8+q)*OCTS + r*8];
            #pragma unroll
            for (int nt = 0; nt < 4; nt++){
                short8 b0 = *(const short8*)&W[6240 + q*OCT + (nt*16 + r)*8];
                short8 b1 = *(const short8*)&W[6240 + (4+q)*OCT + (nt*16 + r)*8];
                f32x4 c = {0.f, 0.f, 0.f, 0.f};
                c = __builtin_amdgcn_mfma_f32_16x16x32_bf16(a0, b0, c, 0, 0, 0);
                c = __builtin_amdgcn_mfma_f32_16x16x32_bf16(a1, b1, c, 0, 0, 0);
                int n = nt*16 + r;
                R[(size_t)p0*64 + n] = f2b_rne(c[0]);
                R[(size_t)p1*64 + n] = f2b_rne(c[1]);
                R[(size_t)p2*64 + n] = f2b_rne(c[2]);
                R[(size_t)p3*64 + n] = f2b_rne(c[3]);
            }
        }
    }
}

// ---------------- fused gather + node update + readout ----------------
template<int LAST>
__global__ __launch_bounds__(256) void k_gnode(const int* __restrict__ offs,
        const int* __restrict__ ssnd, const float* __restrict__ h, const u16* __restrict__ R,
        const float* __restrict__ nf, const float* __restrict__ attrs,
        const float* __restrict__ Wmix0, const float* __restrict__ Wsc,
        const float* __restrict__ Wprod, const float* __restrict__ Wtail,
        const float* __restrict__ Wml2, const float* __restrict__ Wup1,
        float* __restrict__ nf1out, float* __restrict__ hout,
        void* __restrict__ out, const int* __restrict__ flag){
    int wv = threadIdx.x >> 6;
    int n  = blockIdx.x * 4 + wv;
    int l  = threadIdx.x & 63;
    int beg = __builtin_amdgcn_readfirstlane(offs[n]);
    int end = __builtin_amdgcn_readfirstlane(offs[n+1]);
    float acc = 0.f;
    // register-cached senders: one coalesced wave-load per 64-edge segment,
    // then v_readlane; 8-deep unroll keeps 16 loads in flight.
    for (int c = beg; c < end; c += 64){
        int ld = c + l; if (ld >= end) ld = end - 1;
        int sv = ssnd[ld];
        int m = end - c; if (m > 64) m = 64;
        int j = 0;
        for (; j + 8 <= m; j += 8){
            int s0 = __builtin_amdgcn_readlane(sv, j+0);
            int s1 = __builtin_amdgcn_readlane(sv, j+1);
            int s2 = __builtin_amdgcn_readlane(sv, j+2);
            int s3 = __builtin_amdgcn_readlane(sv, j+3);
            int s4 = __builtin_amdgcn_readlane(sv, j+4);
            int s5 = __builtin_amdgcn_readlane(sv, j+5);
            int s6 = __builtin_amdgcn_readlane(sv, j+6);
            int s7 = __builtin_amdgcn_readlane(sv, j+7);
            float r0 = b2f(R[(size_t)(c+j+0)*64 + l]);
            float r1 = b2f(R[(size_t)(c+j+1)*64 + l]);
            float r2 = b2f(R[(size_t)(c+j+2)*64 + l]);
            float r3 = b2f(R[(size_t)(c+j+3)*64 + l]);
            float r4 = b2f(R[(size_t)(c+j+4)*64 + l]);
            float r5 = b2f(R[(size_t)(c+j+5)*64 + l]);
            float r6 = b2f(R[(size_t)(c+j+6)*64 + l]);
            float r7 = b2f(R[(size_t)(c+j+7)*64 + l]);
            float a0 = h[s0*64 + l]*r0 + h[s1*64 + l]*r1;
            float a1 = h[s2*64 + l]*r2 + h[s3*64 + l]*r3;
            float a2 = h[s4*64 + l]*r4 + h[s5*64 + l]*r5;
            float a3 = h[s6*64 + l]*r6 + h[s7*64 + l]*r7;
            acc += (a0 + a1) + (a2 + a3);
        }
        for (; j + 4 <= m; j += 4){
            int s0 = __builtin_amdgcn_readlane(sv, j+0);
            int s1 = __builtin_amdgcn_readlane(sv, j+1);
            int s2 = __builtin_amdgcn_readlane(sv, j+2);
            int s3 = __builtin_amdgcn_readlane(sv, j+3);
            float r0 = b2f(R[(size_t)(c+j+0)*64 + l]);
            float r1 = b2f(R[(size_t)(c+j+1)*64 + l]);
            float r2 = b2f(R[(size_t)(c+j+2)*64 + l]);
            float r3 = b2f(R[(size_t)(c+j+3)*64 + l]);
            acc += h[s0*64 + l]*r0 + h[s1*64 + l]*r1 + h[s2*64 + l]*r2 + h[s3*64 + l]*r3;
        }
        for (; j < m; j++){
            int s = __builtin_amdgcn_readlane(sv, j);
            acc += h[s*64 + l] * b2f(R[(size_t)(c+j)*64 + l]);
        }
    }
    float Af  = acc * 0.0625f;
    float nff = nf[n*64 + l];
    float am = 0.f;
    #pragma unroll 16
    for (int f = 0; f < 64; f++) am += __shfl(Af, f) * Wmix0[f*64 + l];
    float sc = 0.f;
    for (int s = 0; s < 10; s++){
        float av = attrs[n*10 + s];       // wave-uniform
        if (av != 0.f){
            const float* Ws = Wsc + s*4096;
            float t = 0.f;
            #pragma unroll 16
            for (int f = 0; f < 64; f++) t += __shfl(nff, f) * Ws[f*64 + l];
            sc += av * t;
        }
    }
    float poly = Wprod[l] + Wprod[64 + l]*am + Wprod[128 + l]*am*am;
    float val = am*poly + sc;
    float rv;
    if (LAST == 0){
        nf1out[n*64 + l] = val;
        float hv = 0.f;
        #pragma unroll 16
        for (int g = 0; g < 64; g++) hv += __shfl(val, g) * Wup1[g*64 + l];
        hout[n*64 + l] = hv;              // separate buffer: h is still being gathered by other blocks
        rv = val * Wtail[l];
    } else {
        int lj = l & 15;                  // all 64 lanes run the shfl loop (divergent shfl is UB)
        float t = 0.f;
        #pragma unroll 16
        for (int g = 0; g < 64; g++){
            float vg = __shfl(val, g);
            t += vg * Wtail[g*16 + lj];
        }
        rv = (l < 16) ? (silu_f(t) * Wml2[lj]) : 0.f;
    }
    #pragma unroll
    for (int o2 = 32; o2; o2 >>= 1) rv += __shfl_down(rv, o2);
    if (l == 0){
        int idx = 2*n + LAST;
        if (flag[0] > 100) ((__hip_bfloat16*)out)[idx] = __float2bfloat16(rv);
        else               ((float*)out)[idx] = rv;
    }
}

// ---------------- legacy fused msg + node (fallback tier only) ----------------
__global__ __launch_bounds__(256) void k_msg_fused(const int* __restrict__ offs,
        const int* __restrict__ ssnd, const float* __restrict__ h, const float* __restrict__ bessp,
        const float* __restrict__ W1, const float* __restrict__ W2, const float* __restrict__ W3,
        float* __restrict__ A){
    int wv = threadIdx.x >> 6;
    int n  = blockIdx.x * 4 + wv;
    int l  = threadIdx.x & 63;
    float w1c[8];
    #pragma unroll
    for (int i = 0; i < 8; i++) w1c[i] = W1[i*64 + l];
    float w2c[64];
    #pragma unroll
    for (int j = 0; j < 64; j++) w2c[j] = W2[j*64 + l];
    float w3c[64];
    #pragma unroll
    for (int j = 0; j < 64; j++) w3c[j] = W3[j*256 + 4*l];
    float acc = 0.f;
    int beg = __builtin_amdgcn_readfirstlane(offs[n]);
    int end = __builtin_amdgcn_readfirstlane(offs[n+1]);
    for (int p = beg; p < end; p++){
        int s = __builtin_amdgcn_readfirstlane(ssnd[p]);
        const float* be = bessp + (size_t)p*8;
        float h1 = 0.f;
        #pragma unroll
        for (int i = 0; i < 8; i++) h1 += be[i] * w1c[i];
        h1 = silu_f(h1);
        float h2 = 0.f;
        #pragma unroll
        for (int j = 0; j < 64; j++) h2 += __shfl(h1, j) * w2c[j];
        h2 = silu_f(h2);
        float rr = 0.f;
        #pragma unroll
        for (int j = 0; j < 64; j++) rr += __shfl(h2, j) * w3c[j];
        acc += h[s*64 + l] * rr;
    }
    A[n*64 + l] = acc * 0.0625f;
}
template<int LAST>
__global__ __launch_bounds__(256) void k_node(const float* __restrict__ A, const float* __restrict__ nf,
        const float* __restrict__ attrs, const float* __restrict__ Wmix0, const float* __restrict__ Wsc,
        const float* __restrict__ Wprod, const float* __restrict__ Wtail, const float* __restrict__ Wml2,
        const float* __restrict__ Wup1, float* __restrict__ nf1out, float* __restrict__ hout,
        void* __restrict__ out, const int* __restrict__ flag){
    int wv = threadIdx.x >> 6;
    int n  = blockIdx.x * 4 + wv;
    int l  = threadIdx.x & 63;
    float Af  = A[n*64 + l];
    float nff = nf[n*64 + l];
    float am = 0.f;
    #pragma unroll 16
    for (int f = 0; f < 64; f++) am += __shfl(Af, f) * Wmix0[f*64 + l];
    float sc = 0.f;
    for (int s = 0; s < 10; s++){
        float av = attrs[n*10 + s];
        if (av != 0.f){
            const float* Ws = Wsc + s*4096;
            float t = 0.f;
            #pragma unroll 16
            for (int f = 0; f < 64; f++) t += __shfl(nff, f) * Ws[f*64 + l];
            sc += av * t;
        }
    }
    float poly = Wprod[l] + Wprod[64 + l]*am + Wprod[128 + l]*am*am;
    float val = am*poly + sc;
    float rv;
    if (LAST == 0){
        nf1out[n*64 + l] = val;
        float hv = 0.f;
        #pragma unroll 16
        for (int g = 0; g < 64; g++) hv += __shfl(val, g) * Wup1[g*64 + l];
        hout[n*64 + l] = hv;
        rv = val * Wtail[l];
    } else {
        int lj = l & 15;
        float t = 0.f;
        #pragma unroll 16
        for (int g = 0; g < 64; g++){
            float vg = __shfl(val, g);
            t += vg * Wtail[g*16 + lj];
        }
        rv = (l < 16) ? (silu_f(t) * Wml2[lj]) : 0.f;
    }
    #pragma unroll
    for (int o2 = 32; o2; o2 >>= 1) rv += __shfl_down(rv, o2);
    if (l == 0){
        int idx = 2*n + LAST;
        if (flag[0] > 100) ((__hip_bfloat16*)out)[idx] = __float2bfloat16(rv);
        else               ((float*)out)[idx] = rv;
    }
}

// ---------------- launch ----------------
extern "C" void kernel_launch(void* const* d_in, const int* in_sizes, int n_in,
                              void* d_out, int out_size, void* d_ws, size_t ws_size,
                              hipStream_t stream) {
    int*   iw = (int*)d_ws;
    float* fw = (float*)d_ws;
    const int* snd = (const int*)d_in[3];
    const int* rcv = (const int*)d_in[4];

    PrepArgs pa;
    const int    pidx[21] = {0,1,2, 5,6,7,8,9,10,11,12,13,14,15,16,17,18,19,20,21,22};
    const size_t pdst[21] = {W_ATT, W_ATT, W_ATT,      // slots 0,2 dead (n=0); 1 = attrs
        W_WGT+OW_EMB, W_WGT+OW_UP0, W_WGT+OW_R10, W_WGT+OW_R20, W_WGT+OW_R30,
        W_WGT+OW_MIX0, W_WGT+OW_SC0, W_WGT+OW_PR0,
        W_WGT+OW_UP1, W_WGT+OW_R11, W_WGT+OW_R21, W_WGT+OW_R31,
        W_WGT+OW_MIX1, W_WGT+OW_SC1, W_WGT+OW_PR1,
        W_WGT+OW_RD0, W_WGT+OW_ML1, W_WGT+OW_ML2};
    // pos (0) and shifts (2) conversions are DEAD (mlp/scatter read raw inputs) -> n=0
    const int    pn[21]   = {0, 100000, 0,
        640, 4096, 512, 4096, 16384, 16384, 40960, 192,
        4096, 512, 4096, 16384, 16384, 40960, 192, 64, 1024, 16};
    for (int i = 0; i < 21; i++){
        pa.s[i] = d_in[pidx[i]];
        pa.d[i] = fw + pdst[i];
        pa.n[i] = pn[i];
    }

    const int dual   = (ws_size >= NEED_DUAL);
    const int single = (!dual && ws_size >= NEED_SINGLE);
    const size_t wp  = dual ? WP_DUAL : (single ? WP_SINGLE : WP_F);
    int* rank = iw + W_BES;   // [E]; fallback bessel reuses this region strictly after scatter

    hipMemsetAsync(iw, 0, (W_CNT + NN) * sizeof(int), stream);   // flag + cnt
    k_dh<<<NE/256, 256, 0, stream>>>((const uint32_t*)d_in[1], rcv, iw + W_FLAG, iw + W_CNT, rank);
    k_scan_prep<<<692, 1024, 0, stream>>>(pa, iw + W_FLAG, iw + W_CNT, iw + W_OFFS,
                                          (u16*)(fw + wp), fw + W_NF0, fw + W_H);

    if (dual){
        k_mlp_mfma<<<1250, 256, 0, stream>>>(rcv, snd, d_in[0], d_in[2],
                                             iw + W_OFFS, rank,
                                             (const u16*)(fw + wp), (const u16*)(fw + wp) + 10400,
                                             iw + W_SSND, (u16*)(fw + W_R0), (u16*)(fw + W_R1),
                                             625, iw + W_FLAG);
        k_gnode<0><<<NN/4, 256, 0, stream>>>(iw+W_OFFS, iw+W_SSND, fw+W_H, (const u16*)(fw+W_R0),
            fw+W_NF0, fw+W_ATT, fw+W_WGT+OW_MIX0, fw+W_WGT+OW_SC0, fw+W_WGT+OW_PR0,
            fw+W_WGT+OW_RD0, nullptr, fw+W_WGT+OW_UP1, fw+W_NF1, fw+W_A, d_out, iw+W_FLAG);
        k_gnode<1><<<NN/4, 256, 0, stream>>>(iw+W_OFFS, iw+W_SSND, fw+W_A, (const u16*)(fw+W_R1),
            fw+W_NF1, fw+W_ATT, fw+W_WGT+OW_MIX1, fw+W_WGT+OW_SC1, fw+W_WGT+OW_PR1,
            fw+W_WGT+OW_ML1, fw+W_WGT+OW_ML2, nullptr, nullptr, nullptr, d_out, iw+W_FLAG);
    } else if (single){
        k_mlp_mfma<<<625, 256, 0, stream>>>(rcv, snd, d_in[0], d_in[2],
                                            iw + W_OFFS, rank,
                                            (const u16*)(fw + wp), (const u16*)(fw + wp),
                                            iw + W_SSND, (u16*)(fw + W_R0), (u16*)(fw + W_R0),
                                            2000000, iw + W_FLAG);
        k_gnode<0><<<NN/4, 256, 0, stream>>>(iw+W_OFFS, iw+W_SSND, fw+W_H, (const u16*)(fw+W_R0),
            fw+W_NF0, fw+W_ATT, fw+W_WGT+OW_MIX0, fw+W_WGT+OW_SC0, fw+W_WGT+OW_PR0,
            fw+W_WGT+OW_RD0, nullptr, fw+W_WGT+OW_UP1, fw+W_NF1, fw+W_A, d_out, iw+W_FLAG);
        k_mlp_mfma<<<625, 256, 0, stream>>>(rcv, snd, d_in[0], d_in[2],
                                            iw + W_OFFS, rank,
                                            (const u16*)(fw + wp) + 10400, (const u16*)(fw + wp) + 10400,
                                            iw + W_SSND, (u16*)(fw + W_R0), (u16*)(fw + W_R0),
                                            2000000, iw + W_FLAG);
        k_gnode<1><<<NN/4, 256, 0, stream>>>(iw+W_OFFS, iw+W_SSND, fw+W_A, (const u16*)(fw+W_R0),
            fw+W_NF1, fw+W_ATT, fw+W_WGT+OW_MIX1, fw+W_WGT+OW_SC1, fw+W_WGT+OW_PR1,
            fw+W_WGT+OW_ML1, fw+W_WGT+OW_ML2, nullptr, nullptr, nullptr, d_out, iw+W_FLAG);
    } else {
        // fallback tier: scatter + bessel buffer + VALU msg kernels (rs lives at W_R0 slot)
        k_scatter_r<<<NE/256, 256, 0, stream>>>(rcv, snd, d_in[0], d_in[2],
                                                iw + W_OFFS, rank, iw + W_SSND,
                                                fw + W_RS_F, iw + W_FLAG);
        k_bess<<<NE/256, 256, 0, stream>>>(fw + W_RS_F, fw + W_BES);
        k_msg_fused<<<NN/4, 256, 0, stream>>>(iw+W_OFFS, iw+W_SSND, fw+W_H, fw+W_BES,
                                              fw+W_WGT+OW_R10, fw+W_WGT+OW_R20,
                                              fw+W_WGT+OW_R30, fw + W_A);
        k_node<0><<<NN/4, 256, 0, stream>>>(fw + W_A, fw + W_NF0, fw + W_ATT,
                                            fw + W_WGT + OW_MIX0, fw + W_WGT + OW_SC0,
                                            fw + W_WGT + OW_PR0, fw + W_WGT + OW_RD0, nullptr,
                                            fw + W_WGT + OW_UP1, fw + W_NF1, fw + W_H,
                                            d_out, iw + W_FLAG);
        k_msg_fused<<<NN/4, 256, 0, stream>>>(iw+W_OFFS, iw+W_SSND, fw+W_H, fw+W_BES,
                                              fw+W_WGT+OW_R11, fw+W_WGT+OW_R21,
                                              fw+W_WGT+OW_R31, fw + W_A);
        k_node<1><<<NN/4, 256, 0, stream>>>(fw + W_A, fw + W_NF1, fw + W_ATT,
                                            fw + W_WGT + OW_MIX1, fw + W_WGT + OW_SC1,
                                            fw + W_WGT + OW_PR1, fw + W_WGT + OW_ML1,
                                            fw + W_WGT + OW_ML2, nullptr, nullptr, nullptr,
                                            d_out, iw + W_FLAG);
    }
}